// Round 4
// baseline (2053.889 us; speedup 1.0000x reference)
//
#include <hip/hip_runtime.h>

#define BATCH 16384
#define NT 26
#define ED 128
#define TOPIN 506    // 128 + 378 (logical width)
#define TLD 512      // padded leading dim of top-input buffer

typedef __attribute__((ext_vector_type(8))) short short8v;   // 8 bf16 (4 VGPR)
typedef __attribute__((ext_vector_type(4))) float f32x4;

// ---------------- bf16 split helpers (RNE) ----------------
__device__ __forceinline__ unsigned short f2bf(float x) {
    union { float f; unsigned u; } c; c.f = x;
    unsigned r = c.u + 0x7FFFu + ((c.u >> 16) & 1u);
    return (unsigned short)(r >> 16);
}
__device__ __forceinline__ float bf2f(unsigned short h) {
    union { float f; unsigned u; } c; c.u = ((unsigned)h) << 16;
    return c.f;
}
__device__ __forceinline__ void bsplit(float x, unsigned short& hi, unsigned short& lo) {
    hi = f2bf(x);
    lo = f2bf(x - bf2f(hi));
}

// async global->LDS, 16B per lane (wave-uniform LDS base + lane*16)
__device__ __forceinline__ void gload16(const void* g, void* l) {
    __builtin_amdgcn_global_load_lds(
        (const __attribute__((address_space(1))) void*)g,
        (__attribute__((address_space(3))) void*)l, 16, 0, 0);
}

// ---------------------------------------------------------------------------
// fp32 GEMM (bottom MLP): C[M][N] = relu(A[M][lda] @ W[K][N] + bias[N])
// 128x128 tile, 256 threads, 8x8 microtile, K-tile 16.
// ---------------------------------------------------------------------------
template<int RELU>
__global__ __launch_bounds__(256) void gemm128(
    const float* __restrict__ A, int lda,
    const float* __restrict__ W,
    const float* __restrict__ bias,
    float* __restrict__ C, int ldc,
    int M, int N, int K)
{
    __shared__ float As[16][132];
    __shared__ float Bs[16][132];

    const int tid = threadIdx.x;
    const int m0 = blockIdx.y * 128;
    const int n0 = blockIdx.x * 128;
    const int tx = tid & 15;
    const int ty = tid >> 4;
    const int lm = tid >> 2;
    const int lk = (tid & 3) * 4;
    const int bk = tid >> 5;
    const int bn = (tid & 31) * 4;
    const bool alignedA = ((lda & 3) == 0);

    float acc[2][2][4][4];
#pragma unroll
    for (int mb = 0; mb < 2; ++mb)
#pragma unroll
        for (int nb = 0; nb < 2; ++nb)
#pragma unroll
            for (int i = 0; i < 4; ++i)
#pragma unroll
                for (int j = 0; j < 4; ++j) acc[mb][nb][i][j] = 0.f;

    for (int k0 = 0; k0 < K; k0 += 16) {
        const bool fullTile = alignedA && (k0 + 16 <= K);
#pragma unroll
        for (int h = 0; h < 2; ++h) {
            const int m = lm + h * 64;
            const float* arow = A + (long)(m0 + m) * lda;
            if (fullTile) {
                const float4 a4 = *(const float4*)(arow + k0 + lk);
                As[lk + 0][m] = a4.x; As[lk + 1][m] = a4.y;
                As[lk + 2][m] = a4.z; As[lk + 3][m] = a4.w;
            } else {
#pragma unroll
                for (int j = 0; j < 4; ++j) {
                    const int k = k0 + lk + j;
                    As[lk + j][m] = (k < K) ? arow[k] : 0.f;
                }
            }
        }
#pragma unroll
        for (int h = 0; h < 2; ++h) {
            const int kr = bk + h * 8;
            const int k = k0 + kr;
            float4 b4 = make_float4(0.f, 0.f, 0.f, 0.f);
            if (k < K) b4 = *(const float4*)(W + (long)k * N + n0 + bn);
            Bs[kr][bn + 0] = b4.x; Bs[kr][bn + 1] = b4.y;
            Bs[kr][bn + 2] = b4.z; Bs[kr][bn + 3] = b4.w;
        }
        __syncthreads();

#pragma unroll
        for (int kk = 0; kk < 16; ++kk) {
            const float4 a0 = *(const float4*)&As[kk][ty * 4];
            const float4 a1 = *(const float4*)&As[kk][64 + ty * 4];
            const float4 b0 = *(const float4*)&Bs[kk][tx * 4];
            const float4 b1 = *(const float4*)&Bs[kk][64 + tx * 4];
            const float av[2][4] = {{a0.x, a0.y, a0.z, a0.w}, {a1.x, a1.y, a1.z, a1.w}};
            const float bv[2][4] = {{b0.x, b0.y, b0.z, b0.w}, {b1.x, b1.y, b1.z, b1.w}};
#pragma unroll
            for (int mb = 0; mb < 2; ++mb)
#pragma unroll
                for (int i = 0; i < 4; ++i)
#pragma unroll
                    for (int nb = 0; nb < 2; ++nb)
#pragma unroll
                        for (int j = 0; j < 4; ++j)
                            acc[mb][nb][i][j] = fmaf(av[mb][i], bv[nb][j], acc[mb][nb][i][j]);
        }
        __syncthreads();
    }

#pragma unroll
    for (int nb = 0; nb < 2; ++nb) {
        const float4 bv = *(const float4*)(bias + n0 + nb * 64 + tx * 4);
#pragma unroll
        for (int mb = 0; mb < 2; ++mb)
#pragma unroll
            for (int i = 0; i < 4; ++i) {
                const int m = m0 + mb * 64 + ty * 4 + i;
                float4 r;
                r.x = acc[mb][nb][i][0] + bv.x;
                r.y = acc[mb][nb][i][1] + bv.y;
                r.z = acc[mb][nb][i][2] + bv.z;
                r.w = acc[mb][nb][i][3] + bv.w;
                if (RELU) {
                    r.x = fmaxf(r.x, 0.f); r.y = fmaxf(r.y, 0.f);
                    r.z = fmaxf(r.z, 0.f); r.w = fmaxf(r.w, 0.f);
                }
                *(float4*)(C + (long)m * ldc + n0 + nb * 64 + tx * 4) = r;
            }
    }
}

// ---------------------------------------------------------------------------
// Split-bf16 MFMA GEMM: C = act(A @ B^T + bias)
// A as hi/lo bf16 [M][Kp]; B as hi/lo bf16 [N][Kp] (pre-transposed weights).
// 128x128 tile, 4 waves (2x2), each wave 64x64 via 4x4 frags of 16x16x32.
// Terms: AhBh + AhBl + AlBh (~fp32 accuracy). Staging via global_load_lds
// width=16 (linear LDS layout = wave-uniform base + lane*16 contract).
// OUTBF=1: writes hi/lo bf16 pair; OUTBF=0: writes fp32.
// Requires M%128==0, N%128==0, Kp%32==0.
// ---------------------------------------------------------------------------
template<int RELU, int OUTBF>
__global__ __launch_bounds__(256) void mfma_gemm(
    const unsigned short* __restrict__ Ah, const unsigned short* __restrict__ Al,
    const unsigned short* __restrict__ Bh, const unsigned short* __restrict__ Bl,
    const float* __restrict__ bias,
    unsigned short* __restrict__ Ch, unsigned short* __restrict__ Cl,
    float* __restrict__ Cf,
    int N, int Kp)
{
    __shared__ unsigned short sA[2][128 * 32];   // [hi/lo][row*32 + k] linear
    __shared__ unsigned short sB[2][128 * 32];

    const int tid  = threadIdx.x;
    const int lane = tid & 63;
    const int wv   = tid >> 6;
    const int m0 = blockIdx.y * 128;
    const int n0 = blockIdx.x * 128;
    const int wr = wv >> 1;       // wave row 0..1 (64-row slab)
    const int wc = wv & 1;        // wave col 0..1 (64-col slab)

    f32x4 acc[4][4];
#pragma unroll
    for (int mi = 0; mi < 4; ++mi)
#pragma unroll
        for (int ni = 0; ni < 4; ++ni) acc[mi][ni] = (f32x4)0.f;

    const int fr = lane & 15;            // fragment row/col
    const int fk = (lane >> 4) * 8;      // fragment k base

    for (int k0 = 0; k0 < Kp; k0 += 32) {
        // --- stage: 4 streams x 2 phases, DMA direct to LDS ---
#pragma unroll
        for (int j = 0; j < 2; ++j) {
            const int c    = j * 256 + tid;            // chunk 0..511 (per-lane)
            const int row  = c >> 2;                   // 0..127
            const int slot = (c & 3) * 8;              // k offset {0,8,16,24}
            const int lb   = (j * 256 + wv * 64) * 8;  // wave base (ushort units)
            const long ga = (long)(m0 + row) * Kp + k0 + slot;
            const long gb = (long)(n0 + row) * Kp + k0 + slot;
            gload16(Ah + ga, &sA[0][lb]);
            gload16(Al + ga, &sA[1][lb]);
            gload16(Bh + gb, &sB[0][lb]);
            gload16(Bl + gb, &sB[1][lb]);
        }
        __syncthreads();   // compiler drains vmcnt before barrier

        short8v ah[4], al[4], bh[4], bl[4];
#pragma unroll
        for (int mi = 0; mi < 4; ++mi) {
            const int r = wr * 64 + mi * 16 + fr;
            ah[mi] = *(const short8v*)&sA[0][r * 32 + fk];
            al[mi] = *(const short8v*)&sA[1][r * 32 + fk];
        }
#pragma unroll
        for (int ni = 0; ni < 4; ++ni) {
            const int c = wc * 64 + ni * 16 + fr;
            bh[ni] = *(const short8v*)&sB[0][c * 32 + fk];
            bl[ni] = *(const short8v*)&sB[1][c * 32 + fk];
        }
#pragma unroll
        for (int mi = 0; mi < 4; ++mi)
#pragma unroll
            for (int ni = 0; ni < 4; ++ni) {
                acc[mi][ni] = __builtin_amdgcn_mfma_f32_16x16x32_bf16(ah[mi], bh[ni], acc[mi][ni], 0, 0, 0);
                acc[mi][ni] = __builtin_amdgcn_mfma_f32_16x16x32_bf16(ah[mi], bl[ni], acc[mi][ni], 0, 0, 0);
                acc[mi][ni] = __builtin_amdgcn_mfma_f32_16x16x32_bf16(al[mi], bh[ni], acc[mi][ni], 0, 0, 0);
            }
        __syncthreads();
    }

    // epilogue: C/D layout col = lane&15, row = (lane>>4)*4 + r  [m89-verified]
    const int rq = lane >> 4;
#pragma unroll
    for (int ni = 0; ni < 4; ++ni) {
        const int col = n0 + wc * 64 + ni * 16 + fr;
        const float bv = bias[col];
#pragma unroll
        for (int mi = 0; mi < 4; ++mi) {
            const int rbase = m0 + wr * 64 + mi * 16 + rq * 4;
#pragma unroll
            for (int r = 0; r < 4; ++r) {
                float v = acc[mi][ni][r] + bv;
                if (RELU) v = fmaxf(v, 0.f);
                const long o = (long)(rbase + r) * N + col;
                if (OUTBF) {
                    unsigned short hi, lo; bsplit(v, hi, lo);
                    Ch[o] = hi; Cl[o] = lo;
                } else {
                    Cf[o] = v;
                }
            }
        }
    }
}

// ---------------------------------------------------------------------------
// Weight transpose + split: W[K][N] fp32 -> Wth/Wtl [N][Kp] bf16 (k>=K -> 0)
// ---------------------------------------------------------------------------
__global__ __launch_bounds__(256) void transpose_split(
    const float* __restrict__ W, int K, int N, int Kp,
    unsigned short* __restrict__ Wth, unsigned short* __restrict__ Wtl)
{
    __shared__ float tile[32][33];
    const int kt = blockIdx.x * 32;
    const int nt = blockIdx.y * 32;
    const int tx = threadIdx.x & 31;
    const int ty = threadIdx.x >> 5;   // 0..7
#pragma unroll
    for (int s = 0; s < 4; ++s) {
        const int k = kt + ty + s * 8;
        tile[ty + s * 8][tx] = (k < K) ? W[(long)k * N + nt + tx] : 0.f;
    }
    __syncthreads();
#pragma unroll
    for (int s = 0; s < 4; ++s) {
        const int nn = ty + s * 8;
        const float v = tile[tx][nn];
        unsigned short hi, lo; bsplit(v, hi, lo);
        const long o = (long)(nt + nn) * Kp + kt + tx;
        Wth[o] = hi; Wtl[o] = lo;
    }
}

// ---------------------------------------------------------------------------
// Activation split: X fp32 [n] -> Xh, Xl bf16 [n]  (n % 1024 == 0)
// ---------------------------------------------------------------------------
__global__ __launch_bounds__(256) void split_act(
    const float* __restrict__ X,
    unsigned short* __restrict__ Xh, unsigned short* __restrict__ Xl)
{
    const long i = ((long)blockIdx.x * 256 + threadIdx.x) * 4;
    const float4 v = *(const float4*)(X + i);
    ushort4 h, l;
    bsplit(v.x, h.x, l.x); bsplit(v.y, h.y, l.y);
    bsplit(v.z, h.z, l.z); bsplit(v.w, h.w, l.w);
    *(ushort4*)(Xh + i) = h;
    *(ushort4*)(Xl + i) = l;
}

// ---------------------------------------------------------------------------
// Fused embedding gather + self-interaction (fp32, T has ld TLD).
// ---------------------------------------------------------------------------
__global__ __launch_bounds__(256) void interact_kernel(
    float* __restrict__ T,
    const int* __restrict__ cat,
    const float* __restrict__ emb)
{
    const int b = blockIdx.x;
    __shared__ float s[128][29];
    const int tid = threadIdx.x;
    float* trow = T + (long)b * TLD;

    for (int idx = tid; idx < 27 * ED; idx += 256) {
        const int row = idx >> 7;
        const int col = idx & 127;
        float v;
        if (row == 0) {
            v = trow[col];
        } else {
            const int t = row - 1;
            const long r = (long)t * 100000 + cat[(long)b * NT + t];
            v = emb[r * ED + col];
        }
        s[col][row] = v;
    }
    if (tid < TLD - TOPIN) trow[TOPIN + tid] = 0.f;
    __syncthreads();

    for (int e = tid; e < 378; e += 256) {
        int i = 0, base = 0;
        while (base + (27 - i) <= e) { base += 27 - i; ++i; }
        const int j = i + (e - base);
        float acc = 0.f;
#pragma unroll 8
        for (int k = 0; k < ED; ++k) acc += s[k][i] * s[k][j];
        trow[128 + e] = acc;
    }
}

// ---------------------------------------------------------------------------
// Final layer: out[b] = A[b](256) . w(256) + bias
// ---------------------------------------------------------------------------
__global__ __launch_bounds__(256) void final_kernel(
    const float* __restrict__ A,
    const float* __restrict__ w,
    const float* __restrict__ bias,
    float* __restrict__ out)
{
    const int wv = threadIdx.x >> 6;
    const int lane = threadIdx.x & 63;
    const int row = blockIdx.x * 4 + wv;
    const float4 a = *(const float4*)(A + (long)row * 256 + lane * 4);
    const float4 ww = *(const float4*)(w + lane * 4);
    float acc = a.x * ww.x + a.y * ww.y + a.z * ww.z + a.w * ww.w;
#pragma unroll
    for (int off = 32; off; off >>= 1) acc += __shfl_down(acc, off);
    if (lane == 0) out[row] = acc + bias[0];
}

// ---------------------------------------------------------------------------
extern "C" void kernel_launch(void* const* d_in, const int* in_sizes, int n_in,
                              void* d_out, int out_size, void* d_ws, size_t ws_size,
                              hipStream_t stream)
{
    const float* dense = (const float*)d_in[0];
    const int*   cat   = (const int*)d_in[1];
    const float* emb   = (const float*)d_in[2];
    const float* bw0 = (const float*)d_in[3];
    const float* bb0 = (const float*)d_in[4];
    const float* bw1 = (const float*)d_in[5];
    const float* bb1 = (const float*)d_in[6];
    const float* bw2 = (const float*)d_in[7];
    const float* bb2 = (const float*)d_in[8];
    const float* tw0 = (const float*)d_in[9];
    const float* tb0 = (const float*)d_in[10];
    const float* tw1 = (const float*)d_in[11];
    const float* tb1 = (const float*)d_in[12];
    const float* tw2 = (const float*)d_in[13];
    const float* tb2 = (const float*)d_in[14];
    const float* tw3 = (const float*)d_in[15];
    const float* tb3 = (const float*)d_in[16];
    const float* tw4 = (const float*)d_in[17];
    const float* tb4 = (const float*)d_in[18];
    float* out = (float*)d_out;

    // ---- workspace layout (~160 MB) ----
    char* w = (char*)d_ws;
    float* ArenaA = (float*)w;                               // 67.1 MB
    float* ArenaB = (float*)(w + (size_t)67108864);          // 67.1 MB
    float* ArenaC = (float*)(w + (size_t)134217728);         // 16.8 MB
    unsigned short* wb = (unsigned short*)(w + (size_t)150994944);
    unsigned short* T0h = wb;                 unsigned short* T0l = T0h + 1024 * 512;
    unsigned short* T1h = T0l + 1024 * 512;   unsigned short* T1l = T1h + 1024 * 1024;
    unsigned short* T2h = T1l + 1024 * 1024;  unsigned short* T2l = T2h + 512 * 1024;
    unsigned short* T3h = T2l + 512 * 1024;   unsigned short* T3l = T3h + 256 * 512;

    // aliased activation buffers (no live-range overlap):
    float* b0out = ArenaA;                                   // [16384][512] fp32
    float* b1out = ArenaC;                                   // [16384][256] fp32
    float* T     = ArenaB;                                   // [16384][512] fp32
    unsigned short* Th  = (unsigned short*)ArenaA;           // [16384][512] bf16
    unsigned short* Tl  = Th + (size_t)BATCH * 512;
    unsigned short* X1h = (unsigned short*)ArenaB;           // [16384][1024]
    unsigned short* X1l = X1h + (size_t)BATCH * 1024;
    unsigned short* X2h = (unsigned short*)ArenaA;           // [16384][1024]
    unsigned short* X2l = X2h + (size_t)BATCH * 1024;
    unsigned short* X3h = (unsigned short*)ArenaB;           // [16384][512]
    unsigned short* X3l = X3h + (size_t)BATCH * 512;
    float* F = ArenaC;                                       // [16384][256] fp32

    const dim3 blk(256);

    // ---- weight transpose + split (small, runs every call) ----
    transpose_split<<<dim3(512 / 32, 1024 / 32), blk, 0, stream>>>(tw0, TOPIN, 1024, 512, T0h, T0l);
    transpose_split<<<dim3(1024 / 32, 1024 / 32), blk, 0, stream>>>(tw1, 1024, 1024, 1024, T1h, T1l);
    transpose_split<<<dim3(1024 / 32, 512 / 32), blk, 0, stream>>>(tw2, 1024, 512, 1024, T2h, T2l);
    transpose_split<<<dim3(512 / 32, 256 / 32), blk, 0, stream>>>(tw3, 512, 256, 512, T3h, T3l);

    // ---- bottom MLP (fp32) ----
    gemm128<1><<<dim3(4, BATCH / 128), blk, 0, stream>>>(dense, 13, bw0, bb0, b0out, 512, BATCH, 512, 13);
    gemm128<1><<<dim3(2, BATCH / 128), blk, 0, stream>>>(b0out, 512, bw1, bb1, b1out, 256, BATCH, 256, 512);
    gemm128<1><<<dim3(1, BATCH / 128), blk, 0, stream>>>(b1out, 256, bw2, bb2, T, TLD, BATCH, 128, 256);

    // ---- gather + interaction (fills T[:,128:506], zeroes pad) ----
    interact_kernel<<<dim3(BATCH), blk, 0, stream>>>(T, cat, emb);

    // ---- split T to bf16 hi/lo ----
    split_act<<<dim3((BATCH * 512) / 1024), blk, 0, stream>>>(T, Th, Tl);

    // ---- top MLP (split-bf16 MFMA) ----
    mfma_gemm<1, 1><<<dim3(1024 / 128, BATCH / 128), blk, 0, stream>>>(
        Th, Tl, T0h, T0l, tb0, X1h, X1l, (float*)nullptr, 1024, 512);
    mfma_gemm<1, 1><<<dim3(1024 / 128, BATCH / 128), blk, 0, stream>>>(
        X1h, X1l, T1h, T1l, tb1, X2h, X2l, (float*)nullptr, 1024, 1024);
    mfma_gemm<1, 1><<<dim3(512 / 128, BATCH / 128), blk, 0, stream>>>(
        X2h, X2l, T2h, T2l, tb2, X3h, X3l, (float*)nullptr, 512, 1024);
    mfma_gemm<1, 0><<<dim3(256 / 128, BATCH / 128), blk, 0, stream>>>(
        X3h, X3l, T3h, T3l, tb3, (unsigned short*)nullptr, (unsigned short*)nullptr, F, 256, 512);

    // ---- final dot ----
    final_kernel<<<dim3(BATCH / 4), blk, 0, stream>>>(F, tw4, tb4, out);
}